// Round 4
// baseline (69.420 us; speedup 1.0000x reference)
//
#include <hip/hip_runtime.h>
#include <math.h>

#define KOSC 64
#define CHUNK 8
#define QH 8                       // q-groups per thread per bank (8*4 = 32 osc)
#define TWO_PI_F  6.28318530717958647692f
#define INV2PI_F  0.15915494309189533577f
#define MIN_SLOPE -2.0f
#define MAX_SLOPE  8.0f

// ---------------------------------------------------------------------------
// Wave-wide (64-lane) reductions for the softmax in the precompute kernel.
// ---------------------------------------------------------------------------
__device__ __forceinline__ float wave_reduce_max(float v) {
#pragma unroll
    for (int off = 32; off > 0; off >>= 1)
        v = fmaxf(v, __shfl_xor(v, off, 64));
    return v;
}
__device__ __forceinline__ float wave_reduce_sum(float v) {
#pragma unroll
    for (int off = 32; off > 0; off >>= 1)
        v += __shfl_xor(v, off, 64);
    return v;
}

// ---------------------------------------------------------------------------
// Precompute per-oscillator constants. 128 threads = 2 waves:
//   wave 0 -> modulator bank, wave 1 -> carrier bank.
// banks[k*8 + c]: c = {f, cd, sd, s, s*off, s*C*dt/tmax, w, w/C}
// scalars = { sig(rev), 1/tmax, dt }
// ---------------------------------------------------------------------------
__global__ void precompute_kernel(
    const float* __restrict__ t, int T,
    const float* __restrict__ cfq, const float* __restrict__ cwt,
    const float* __restrict__ mfq, const float* __restrict__ mwt,
    const float* __restrict__ po,
    const float* __restrict__ ces, const float* __restrict__ ceo,
    const float* __restrict__ mes, const float* __restrict__ meo,
    float* __restrict__ banks, float* __restrict__ scalars)
{
    const int k    = threadIdx.x;     // 0..127
    const int bank = k >> 6;          // 0 = modulator, 1 = carrier
    const int idx  = k & 63;

    const float fq = bank ? cfq[idx] : mfq[idx];
    const float wt = bank ? cwt[idx] : mwt[idx];
    const float sl = bank ? ces[idx] : mes[idx];
    const float of = bank ? ceo[idx] : meo[idx];

    // per-wave softmax over the 64 weights of this bank
    const float mx = wave_reduce_max(wt);
    const float ex = expf(wt - mx);
    const float sm = wave_reduce_sum(ex);
    const float w  = ex / sm;

    // envelope constants
    const float sg   = 1.0f / (1.0f + expf(-sl));
    const float s    = exp2f(sg * (MAX_SLOPE - MIN_SLOPE) + MIN_SLOPE);
    const float offv = tanhf(of) * 0.5f;

    const float dt   = t[1] - t[0];           // t[0]==0 -> exact
    const float tmax = t[T - 1];

    // rotation constants in f64 (one-time cost)
    const double th = (double)TWO_PI_F * (double)fq * (double)dt;
    const float cd  = (float)cos(th);
    const float sd  = (float)sin(th);

    float* B = banks + k * 8;
    B[0] = fq;
    B[1] = cd;
    B[2] = sd;
    B[3] = s;
    B[4] = s * offv;
    B[5] = s * ((float)CHUNK * dt / tmax);    // arg step over a whole chunk
    B[6] = w;
    B[7] = w * (1.0f / (float)CHUNK);

    if (k == 0) {
        scalars[0] = 1.0f / (1.0f + expf(-po[0]));  // phase offset, REVOLUTIONS
        scalars[1] = 1.0f / tmax;
        scalars[2] = dt;
    }
}

// ---------------------------------------------------------------------------
// Oscillator state for the rotation recurrence.
// ---------------------------------------------------------------------------
struct Osc {
    float cd, sd;          // per-step rotation
    float cA, sA;          // phasor state
    float wb, wdb;         // weighted bell + per-step increment
    float wbf, wdbf;       // f * (wb, wdb) for the jitter-correction sums
};

__device__ __forceinline__ void osc_setup(const float* __restrict__ b,
                                          float t0, float tn0, float sig,
                                          Osc& o)
{
    const float f     = b[0];
    o.cd              = b[1];
    o.sd              = b[2];
    const float s     = b[3];
    const float soff  = b[4];
    const float sCdtn = b[5];
    const float w     = b[6];
    const float winvC = b[7];

    // exact phase at chunk start (Dekker product + Sterbenz frac), revolutions
    const float hi  = f * t0;
    const float lo  = fmaf(f, t0, -hi);
    const float rev = (hi - floorf(hi)) + lo + sig;
    o.cA = __builtin_amdgcn_cosf(rev);             // cos(2*pi*rev)
    o.sA = __builtin_amdgcn_sinf(rev);

    // weighted bell, linearly interpolated across the chunk
    const float a0 = fmaf(s, tn0, soff);
    const float aE = a0 + sCdtn;
    const float b0 = __builtin_amdgcn_rsqf(fmaf(a0, a0, 1.0f));
    const float bE = __builtin_amdgcn_rsqf(fmaf(aE, aE, 1.0f));
    o.wb   = b0 * w;
    o.wdb  = (bE - b0) * winvC;
    o.wbf  = o.wb * f;
    o.wdbf = o.wdb * f;
}

// ---------------------------------------------------------------------------
// Main kernel: a PAIR of adjacent threads handles one chunk of 8 samples;
// each thread owns 32 of the 64 oscillators of each bank. Partial sums are
// combined with one shfl_xor(1) per sample (commutative f32 add -> both
// lanes get bit-identical full sums).
//
// Carrier FM factorization: sum_k wb sin(A_k + m) = cm*S + sm*C with
// S = sum wb sinA, C = sum wb cosA; jitter correction uses
// Sf = sum f*wb*sinA, Cf = sum f*wb*cosA:
//   out_j = cm*S + sm*C + d2p_j*(cm*Cf - sm*Sf).
// ---------------------------------------------------------------------------
__global__ void __launch_bounds__(256, 4) fm_main_kernel(
    const float* __restrict__ t,
    const float* __restrict__ banks,
    const float* __restrict__ scalars,
    float* __restrict__ out, int T)
{
    const int tid = blockIdx.x * blockDim.x + threadIdx.x;
    const int p   = tid & 1;              // which half of the oscillators
    const int i0  = (tid >> 1) * CHUNK;   // chunk start sample
    if (i0 >= T) return;

    const float sig     = scalars[0];
    const float invtmax = scalars[1];
    const float dt      = scalars[2];

    const float4 ta = *reinterpret_cast<const float4*>(t + i0);
    const float4 tb = *reinterpret_cast<const float4*>(t + i0 + 4);
    const float tj[CHUNK] = {ta.x, ta.y, ta.z, ta.w, tb.x, tb.y, tb.z, tb.w};
    const float t0 = tj[0];

    // 2*pi * (t_j - (t0 + j*dt)): f32 rounding jitter of t, radians per Hz
    float d2p[CHUNK];
    d2p[0] = 0.0f;
#pragma unroll
    for (int j = 1; j < CHUNK; ++j)
        d2p[j] = TWO_PI_F * fmaf(-(float)j, dt, tj[j] - t0);

    const float tn0 = fmaf(t0, invtmax, -0.5f);

    // ---------------- modulator bank (32 osc): C = sum wb*cA, Sf = sum wbf*sA
    float Cm[CHUNK], Sfm[CHUNK];
#pragma unroll
    for (int j = 0; j < CHUNK; ++j) { Cm[j] = 0.0f; Sfm[j] = 0.0f; }

    {
        const float* base = banks + (p * 32) * 8;
#pragma unroll 1
        for (int q = 0; q < QH; ++q) {
            const float* B = base + q * 32;        // 4 oscillators per group
            Osc o0, o1, o2, o3;
            osc_setup(B +  0, t0, tn0, sig, o0);
            osc_setup(B +  8, t0, tn0, sig, o1);
            osc_setup(B + 16, t0, tn0, sig, o2);
            osc_setup(B + 24, t0, tn0, sig, o3);

#pragma unroll
            for (int j = 0; j < CHUNK; ++j) {
#define MOD_STEP(o)                                                       \
                {                                                         \
                    Cm[j]  = fmaf(o.wb,  o.cA, Cm[j]);                    \
                    Sfm[j] = fmaf(o.wbf, o.sA, Sfm[j]);                   \
                    o.wb  += o.wdb;                                       \
                    o.wbf += o.wdbf;                                      \
                    const float nc = fmaf(-o.sA, o.sd, o.cA * o.cd);      \
                    o.sA = fmaf(o.sA, o.cd, o.cA * o.sd);                 \
                    o.cA = nc;                                            \
                }
                MOD_STEP(o0) MOD_STEP(o1) MOD_STEP(o2) MOD_STEP(o3)
#undef MOD_STEP
            }
        }
    }

    // combine pair partials -> full mod; cm/sm of mod (revolutions)
    float cm[CHUNK], sm[CHUNK];
#pragma unroll
    for (int j = 0; j < CHUNK; ++j) {
        const float mp = fmaf(-d2p[j], Sfm[j], Cm[j]);
        const float m  = mp + __shfl_xor(mp, 1, 64);   // full modulator sum
        const float mrev = m * INV2PI_F;
        cm[j] = __builtin_amdgcn_cosf(mrev);
        sm[j] = __builtin_amdgcn_sinf(mrev);
    }

    // ---------------- carrier bank (32 osc): S, C, Sf, Cf sums --------------
    float S[CHUNK], C[CHUNK], Sf[CHUNK], Cf[CHUNK];
#pragma unroll
    for (int j = 0; j < CHUNK; ++j) { S[j] = 0.0f; C[j] = 0.0f;
                                      Sf[j] = 0.0f; Cf[j] = 0.0f; }

    {
        const float* base = banks + (KOSC + p * 32) * 8;
#pragma unroll 1
        for (int q = 0; q < QH; ++q) {
            const float* B = base + q * 32;        // 4 oscillators per group
            Osc o0, o1, o2, o3;
            osc_setup(B +  0, t0, tn0, sig, o0);
            osc_setup(B +  8, t0, tn0, sig, o1);
            osc_setup(B + 16, t0, tn0, sig, o2);
            osc_setup(B + 24, t0, tn0, sig, o3);

#pragma unroll
            for (int j = 0; j < CHUNK; ++j) {
#define CAR_STEP(o)                                                       \
                {                                                         \
                    S[j]  = fmaf(o.wb,  o.sA, S[j]);                      \
                    C[j]  = fmaf(o.wb,  o.cA, C[j]);                      \
                    Sf[j] = fmaf(o.wbf, o.sA, Sf[j]);                     \
                    Cf[j] = fmaf(o.wbf, o.cA, Cf[j]);                     \
                    o.wb  += o.wdb;                                       \
                    o.wbf += o.wdbf;                                      \
                    const float nc = fmaf(-o.sA, o.sd, o.cA * o.cd);      \
                    o.sA = fmaf(o.sA, o.cd, o.cA * o.sd);                 \
                    o.cA = nc;                                            \
                }
                CAR_STEP(o0) CAR_STEP(o1) CAR_STEP(o2) CAR_STEP(o3)
#undef CAR_STEP
            }
        }
    }

    // epilogue: apply FM rotation + jitter correction, combine pair, store
    float of[CHUNK];
#pragma unroll
    for (int j = 0; j < CHUNK; ++j) {
        float u = cm[j] * S[j];
        u = fmaf(sm[j], C[j], u);
        float v = cm[j] * Cf[j];
        v = fmaf(-sm[j], Sf[j], v);
        const float op = fmaf(d2p[j], v, u);
        of[j] = op + __shfl_xor(op, 1, 64);            // full carrier sum
    }

    float4 w4;
    w4.x = p ? of[4] : of[0];
    w4.y = p ? of[5] : of[1];
    w4.z = p ? of[6] : of[2];
    w4.w = p ? of[7] : of[3];
    *reinterpret_cast<float4*>(out + i0 + p * 4) = w4;
}

// ---------------------------------------------------------------------------
extern "C" void kernel_launch(void* const* d_in, const int* in_sizes, int n_in,
                              void* d_out, int out_size, void* d_ws, size_t ws_size,
                              hipStream_t stream) {
    // setup_inputs() order:
    // 0:t 1:carrier_fq 2:carrier_weight 3:mod_fq 4:mod_weight 5:phase_offset
    // 6:carrier_env_slope 7:carrier_env_offset 8:mod_env_slope 9:mod_env_offset
    const float* t   = (const float*)d_in[0];
    const float* cfq = (const float*)d_in[1];
    const float* cw  = (const float*)d_in[2];
    const float* mfq = (const float*)d_in[3];
    const float* mw  = (const float*)d_in[4];
    const float* po  = (const float*)d_in[5];
    const float* ces = (const float*)d_in[6];
    const float* ceo = (const float*)d_in[7];
    const float* mes = (const float*)d_in[8];
    const float* meo = (const float*)d_in[9];
    const int T = in_sizes[0];

    float* banks   = (float*)d_ws;                       // 128 osc * 8 floats
    float* scalars = banks + 2 * KOSC * 8;               // 3 floats

    precompute_kernel<<<1, 2 * KOSC, 0, stream>>>(t, T, cfq, cw, mfq, mw, po,
                                                  ces, ceo, mes, meo,
                                                  banks, scalars);

    const int threads = (T / CHUNK) * 2;      // pair of threads per chunk
    const int block   = 256;
    const int grid    = (threads + block - 1) / block;
    fm_main_kernel<<<grid, block, 0, stream>>>(t, banks, scalars,
                                               (float*)d_out, T);
}

// Round 5
// 46.899 us; speedup vs baseline: 1.4802x; 1.4802x over previous
//
#include <hip/hip_runtime.h>
#include <math.h>

#define KOSC 64
#define CHUNK 8
#define NSPLIT 4                   // waves per block / oscillator split factor
#define QH 4                       // quads per thread per bank (4*4 = 16 osc)
#define TWO_PI_F  6.28318530717958647692f
#define INV2PI_F  0.15915494309189533577f
#define MIN_SLOPE -2.0f
#define MAX_SLOPE  8.0f

// ---------------------------------------------------------------------------
// Wave-wide (64-lane) reductions for the softmax in the precompute kernel.
// ---------------------------------------------------------------------------
__device__ __forceinline__ float wave_reduce_max(float v) {
#pragma unroll
    for (int off = 32; off > 0; off >>= 1)
        v = fmaxf(v, __shfl_xor(v, off, 64));
    return v;
}
__device__ __forceinline__ float wave_reduce_sum(float v) {
#pragma unroll
    for (int off = 32; off > 0; off >>= 1)
        v += __shfl_xor(v, off, 64);
    return v;
}

// ---------------------------------------------------------------------------
// Precompute per-oscillator constants. 128 threads = 2 waves:
//   wave 0 -> modulator bank, wave 1 -> carrier bank.
// banks[k*8 + c]: c = {f, cd, sd, s, s*off, s*C*dt/tmax, w, w/C}
// scalars = { sig(rev), 1/tmax, dt }
// ---------------------------------------------------------------------------
__global__ void precompute_kernel(
    const float* __restrict__ t, int T,
    const float* __restrict__ cfq, const float* __restrict__ cwt,
    const float* __restrict__ mfq, const float* __restrict__ mwt,
    const float* __restrict__ po,
    const float* __restrict__ ces, const float* __restrict__ ceo,
    const float* __restrict__ mes, const float* __restrict__ meo,
    float* __restrict__ banks, float* __restrict__ scalars)
{
    const int k    = threadIdx.x;     // 0..127
    const int bank = k >> 6;          // 0 = modulator, 1 = carrier
    const int idx  = k & 63;

    const float fq = bank ? cfq[idx] : mfq[idx];
    const float wt = bank ? cwt[idx] : mwt[idx];
    const float sl = bank ? ces[idx] : mes[idx];
    const float of = bank ? ceo[idx] : meo[idx];

    // per-wave softmax over the 64 weights of this bank
    const float mx = wave_reduce_max(wt);
    const float ex = expf(wt - mx);
    const float sm = wave_reduce_sum(ex);
    const float w  = ex / sm;

    // envelope constants
    const float sg   = 1.0f / (1.0f + expf(-sl));
    const float s    = exp2f(sg * (MAX_SLOPE - MIN_SLOPE) + MIN_SLOPE);
    const float offv = tanhf(of) * 0.5f;

    const float dt   = t[1] - t[0];           // t[0]==0 -> exact
    const float tmax = t[T - 1];

    // rotation constants in f64 (one-time cost)
    const double th = (double)TWO_PI_F * (double)fq * (double)dt;
    const float cd  = (float)cos(th);
    const float sd  = (float)sin(th);

    float* B = banks + k * 8;
    B[0] = fq;
    B[1] = cd;
    B[2] = sd;
    B[3] = s;
    B[4] = s * offv;
    B[5] = s * ((float)CHUNK * dt / tmax);    // arg step over a whole chunk
    B[6] = w;
    B[7] = w * (1.0f / (float)CHUNK);

    if (k == 0) {
        scalars[0] = 1.0f / (1.0f + expf(-po[0]));  // phase offset, REVOLUTIONS
        scalars[1] = 1.0f / tmax;
        scalars[2] = dt;
    }
}

// ---------------------------------------------------------------------------
// Oscillator state for the rotation recurrence. The f-weighted envelope
// (wbf) is FROZEN at its chunk-start value: it only scales the O(6e-3)
// jitter-correction term, so its ~1e-3 relative drift over a chunk is
// negligible (<2e-5 absolute).
// ---------------------------------------------------------------------------
struct Osc {
    float cd, sd;          // per-step rotation
    float cA, sA;          // phasor state
    float wb, wdb;         // weighted bell + per-step increment
    float wbf;             // f * wb at chunk start (frozen)
};

__device__ __forceinline__ void osc_setup(const float* __restrict__ b,
                                          float t0, float tn0, float sig,
                                          Osc& o)
{
    const float f     = b[0];
    o.cd              = b[1];
    o.sd              = b[2];
    const float s     = b[3];
    const float soff  = b[4];
    const float sCdtn = b[5];
    const float w     = b[6];
    const float winvC = b[7];

    // exact phase at chunk start (Dekker product + Sterbenz frac), revolutions
    const float hi  = f * t0;
    const float lo  = fmaf(f, t0, -hi);
    const float rev = (hi - floorf(hi)) + lo + sig;
    o.cA = __builtin_amdgcn_cosf(rev);             // cos(2*pi*rev)
    o.sA = __builtin_amdgcn_sinf(rev);

    // weighted bell, linearly interpolated across the chunk
    const float a0 = fmaf(s, tn0, soff);
    const float aE = a0 + sCdtn;
    const float b0 = __builtin_amdgcn_rsqf(fmaf(a0, a0, 1.0f));
    const float bE = __builtin_amdgcn_rsqf(fmaf(aE, aE, 1.0f));
    o.wb  = b0 * w;
    o.wdb = (bE - b0) * winvC;
    o.wbf = o.wb * f;
}

// ---------------------------------------------------------------------------
// Main kernel: each block = 4 waves; the 4 waves SPLIT the 64 oscillators of
// each bank 4-ways (16 osc per thread). p = wave id is WAVE-UNIFORM (forced
// via readfirstlane) so the bank-table pointer stays uniform -> s_load scalar
// path (round-4 regression was losing this). Each of the 64 lanes of a wave
// owns one chunk of 8 samples. Cross-wave partial sums (modulator mid-kernel,
// carrier output) are combined through LDS with two barriers.
//
// Carrier FM factorization: sum_k wb sin(A_k + m) = cm*S + sm*C with
// S = sum wb sinA, C = sum wb cosA; first-order time-jitter correction via
// Sf = sum f*wb*sinA, Cf = sum f*wb*cosA:
//   out_j = cm*S + sm*C + d2p_j*(cm*Cf - sm*Sf).
// ---------------------------------------------------------------------------
__global__ void __launch_bounds__(256, 4) fm_main_kernel(
    const float* __restrict__ t,
    const float* __restrict__ banks,
    const float* __restrict__ scalars,
    float* __restrict__ out, int T)
{
    const int c  = threadIdx.x & 63;                                   // chunk lane
    const int p  = __builtin_amdgcn_readfirstlane(threadIdx.x >> 6);   // wave id
    const int i0 = (blockIdx.x * 64 + c) * CHUNK;                      // sample base

    __shared__ float modbuf[NSPLIT][64][CHUNK];
    __shared__ float outbuf[NSPLIT][64][CHUNK];

    const float sig     = scalars[0];
    const float invtmax = scalars[1];
    const float dt      = scalars[2];

    const float4 ta = *reinterpret_cast<const float4*>(t + i0);
    const float4 tb = *reinterpret_cast<const float4*>(t + i0 + 4);
    const float tj[CHUNK] = {ta.x, ta.y, ta.z, ta.w, tb.x, tb.y, tb.z, tb.w};
    const float t0 = tj[0];

    // 2*pi * (t_j - (t0 + j*dt)): f32 rounding jitter of t, radians per Hz
    float d2p[CHUNK];
    d2p[0] = 0.0f;
#pragma unroll
    for (int j = 1; j < CHUNK; ++j)
        d2p[j] = TWO_PI_F * fmaf(-(float)j, dt, tj[j] - t0);

    const float tn0 = fmaf(t0, invtmax, -0.5f);

    // ---------------- modulator bank (16 osc): Cm = sum wb*cA, Sfm = sum wbf*sA
    float Cm[CHUNK], Sfm[CHUNK];
#pragma unroll
    for (int j = 0; j < CHUNK; ++j) { Cm[j] = 0.0f; Sfm[j] = 0.0f; }

    {
        const float* base = banks + (p * 16) * 8;      // wave-uniform pointer
#pragma unroll 1
        for (int q = 0; q < QH; ++q) {
            const float* B = base + q * 32;            // 4 oscillators per group
            Osc o0, o1, o2, o3;
            osc_setup(B +  0, t0, tn0, sig, o0);
            osc_setup(B +  8, t0, tn0, sig, o1);
            osc_setup(B + 16, t0, tn0, sig, o2);
            osc_setup(B + 24, t0, tn0, sig, o3);

#pragma unroll
            for (int j = 0; j < CHUNK; ++j) {
#define MOD_STEP(o)                                                       \
                {                                                         \
                    Cm[j]  = fmaf(o.wb,  o.cA, Cm[j]);                    \
                    Sfm[j] = fmaf(o.wbf, o.sA, Sfm[j]);                   \
                    o.wb  += o.wdb;                                       \
                    const float nc = fmaf(-o.sA, o.sd, o.cA * o.cd);      \
                    o.sA = fmaf(o.sA, o.cd, o.cA * o.sd);                 \
                    o.cA = nc;                                            \
                }
                MOD_STEP(o0) MOD_STEP(o1) MOD_STEP(o2) MOD_STEP(o3)
#undef MOD_STEP
            }
        }
    }

    // publish partial mod (jitter-corrected), combine across the 4 waves
    {
        float mp[CHUNK];
#pragma unroll
        for (int j = 0; j < CHUNK; ++j)
            mp[j] = fmaf(-d2p[j], Sfm[j], Cm[j]);
        *reinterpret_cast<float4*>(&modbuf[p][c][0]) = make_float4(mp[0], mp[1], mp[2], mp[3]);
        *reinterpret_cast<float4*>(&modbuf[p][c][4]) = make_float4(mp[4], mp[5], mp[6], mp[7]);
    }
    __syncthreads();

    float cm[CHUNK], sm[CHUNK];
#pragma unroll
    for (int j = 0; j < CHUNK; ++j) {
        const float m = ((modbuf[0][c][j] + modbuf[1][c][j])
                        + modbuf[2][c][j]) + modbuf[3][c][j];
        const float mrev = m * INV2PI_F;
        cm[j] = __builtin_amdgcn_cosf(mrev);
        sm[j] = __builtin_amdgcn_sinf(mrev);
    }

    // ---------------- carrier bank (16 osc): S, C, Sf, Cf sums --------------
    float S[CHUNK], C[CHUNK], Sf[CHUNK], Cf[CHUNK];
#pragma unroll
    for (int j = 0; j < CHUNK; ++j) { S[j] = 0.0f; C[j] = 0.0f;
                                      Sf[j] = 0.0f; Cf[j] = 0.0f; }

    {
        const float* base = banks + (KOSC + p * 16) * 8;   // wave-uniform
#pragma unroll 1
        for (int q = 0; q < QH; ++q) {
            const float* B = base + q * 32;
            Osc o0, o1, o2, o3;
            osc_setup(B +  0, t0, tn0, sig, o0);
            osc_setup(B +  8, t0, tn0, sig, o1);
            osc_setup(B + 16, t0, tn0, sig, o2);
            osc_setup(B + 24, t0, tn0, sig, o3);

#pragma unroll
            for (int j = 0; j < CHUNK; ++j) {
#define CAR_STEP(o)                                                       \
                {                                                         \
                    S[j]  = fmaf(o.wb,  o.sA, S[j]);                      \
                    C[j]  = fmaf(o.wb,  o.cA, C[j]);                      \
                    Sf[j] = fmaf(o.wbf, o.sA, Sf[j]);                     \
                    Cf[j] = fmaf(o.wbf, o.cA, Cf[j]);                     \
                    o.wb  += o.wdb;                                       \
                    const float nc = fmaf(-o.sA, o.sd, o.cA * o.cd);      \
                    o.sA = fmaf(o.sA, o.cd, o.cA * o.sd);                 \
                    o.cA = nc;                                            \
                }
                CAR_STEP(o0) CAR_STEP(o1) CAR_STEP(o2) CAR_STEP(o3)
#undef CAR_STEP
            }
        }
    }

    // epilogue: FM rotation + jitter correction -> per-wave partial output
    {
        float op[CHUNK];
#pragma unroll
        for (int j = 0; j < CHUNK; ++j) {
            float u = cm[j] * S[j];
            u = fmaf(sm[j], C[j], u);
            float v = cm[j] * Cf[j];
            v = fmaf(-sm[j], Sf[j], v);
            op[j] = fmaf(d2p[j], v, u);
        }
        *reinterpret_cast<float4*>(&outbuf[p][c][0]) = make_float4(op[0], op[1], op[2], op[3]);
        *reinterpret_cast<float4*>(&outbuf[p][c][4]) = make_float4(op[4], op[5], op[6], op[7]);
    }
    __syncthreads();

    // wave 0 combines the 4 partials and stores 8 samples per lane
    if (p == 0) {
        float of[CHUNK];
#pragma unroll
        for (int j = 0; j < CHUNK; ++j)
            of[j] = ((outbuf[0][c][j] + outbuf[1][c][j])
                    + outbuf[2][c][j]) + outbuf[3][c][j];
        *reinterpret_cast<float4*>(out + i0)     = make_float4(of[0], of[1], of[2], of[3]);
        *reinterpret_cast<float4*>(out + i0 + 4) = make_float4(of[4], of[5], of[6], of[7]);
    }
}

// ---------------------------------------------------------------------------
extern "C" void kernel_launch(void* const* d_in, const int* in_sizes, int n_in,
                              void* d_out, int out_size, void* d_ws, size_t ws_size,
                              hipStream_t stream) {
    // setup_inputs() order:
    // 0:t 1:carrier_fq 2:carrier_weight 3:mod_fq 4:mod_weight 5:phase_offset
    // 6:carrier_env_slope 7:carrier_env_offset 8:mod_env_slope 9:mod_env_offset
    const float* t   = (const float*)d_in[0];
    const float* cfq = (const float*)d_in[1];
    const float* cw  = (const float*)d_in[2];
    const float* mfq = (const float*)d_in[3];
    const float* mw  = (const float*)d_in[4];
    const float* po  = (const float*)d_in[5];
    const float* ces = (const float*)d_in[6];
    const float* ceo = (const float*)d_in[7];
    const float* mes = (const float*)d_in[8];
    const float* meo = (const float*)d_in[9];
    const int T = in_sizes[0];

    float* banks   = (float*)d_ws;                       // 128 osc * 8 floats
    float* scalars = banks + 2 * KOSC * 8;               // 3 floats

    precompute_kernel<<<1, 2 * KOSC, 0, stream>>>(t, T, cfq, cw, mfq, mw, po,
                                                  ces, ceo, mes, meo,
                                                  banks, scalars);

    // one block = 4 waves = 64 chunks of 8 samples
    const int grid = T / (CHUNK * 64);        // 2048 blocks for T = 1<<20
    fm_main_kernel<<<grid, 256, 0, stream>>>(t, banks, scalars,
                                             (float*)d_out, T);
}

// Round 6
// 34.379 us; speedup vs baseline: 2.0193x; 1.3642x over previous
//
#include <hip/hip_runtime.h>
#include <math.h>

#define KOSC 64
#define CHUNK 8
#define NSPLIT 4                   // waves per block / oscillator split factor
#define QH 4                       // quads per thread per bank (4*4 = 16 osc)
#define TWO_PI_F  6.28318530717958647692f
#define INV2PI_F  0.15915494309189533577f
#define MIN_SLOPE -2.0f
#define MAX_SLOPE  8.0f

// ---------------------------------------------------------------------------
// Wave-wide (64-lane) reductions for the softmax in the precompute kernel.
// ---------------------------------------------------------------------------
__device__ __forceinline__ float wave_reduce_max(float v) {
#pragma unroll
    for (int off = 32; off > 0; off >>= 1)
        v = fmaxf(v, __shfl_xor(v, off, 64));
    return v;
}
__device__ __forceinline__ float wave_reduce_sum(float v) {
#pragma unroll
    for (int off = 32; off > 0; off >>= 1)
        v += __shfl_xor(v, off, 64);
    return v;
}

// ---------------------------------------------------------------------------
// Precompute per-oscillator constants. 128 threads = 2 waves:
//   wave 0 -> modulator bank, wave 1 -> carrier bank.
// banks[k*8 + c]: c = {f, cd, sd, 2cd, s, s*off + 3.5*s*dtn, w, 0}
//   (dtn = dt/tmax; slot 5 is the frozen-midpoint envelope-arg constant)
// scalars = { sig(rev), 1/tmax, dt }
// ---------------------------------------------------------------------------
__global__ void precompute_kernel(
    const float* __restrict__ t, int T,
    const float* __restrict__ cfq, const float* __restrict__ cwt,
    const float* __restrict__ mfq, const float* __restrict__ mwt,
    const float* __restrict__ po,
    const float* __restrict__ ces, const float* __restrict__ ceo,
    const float* __restrict__ mes, const float* __restrict__ meo,
    float* __restrict__ banks, float* __restrict__ scalars)
{
    const int k    = threadIdx.x;     // 0..127
    const int bank = k >> 6;          // 0 = modulator, 1 = carrier
    const int idx  = k & 63;

    const float fq = bank ? cfq[idx] : mfq[idx];
    const float wt = bank ? cwt[idx] : mwt[idx];
    const float sl = bank ? ces[idx] : mes[idx];
    const float of = bank ? ceo[idx] : meo[idx];

    // per-wave softmax over the 64 weights of this bank
    const float mx = wave_reduce_max(wt);
    const float ex = expf(wt - mx);
    const float sm = wave_reduce_sum(ex);
    const float w  = ex / sm;

    // envelope constants
    const float sg   = 1.0f / (1.0f + expf(-sl));
    const float s    = exp2f(sg * (MAX_SLOPE - MIN_SLOPE) + MIN_SLOPE);
    const float offv = tanhf(of) * 0.5f;

    const float dt   = t[1] - t[0];           // t[0]==0 -> exact
    const float tmax = t[T - 1];
    const float dtn  = dt / tmax;

    // rotation constants in f64 (one-time cost)
    const double th = (double)TWO_PI_F * (double)fq * (double)dt;
    const float cd  = (float)cos(th);
    const float sd  = (float)sin(th);

    float* B = banks + k * 8;
    B[0] = fq;
    B[1] = cd;
    B[2] = sd;
    B[3] = cd + cd;                            // Chebyshev coefficient 2cos(th)
    B[4] = s;
    B[5] = fmaf(s * dtn, 0.5f * (float)(CHUNK - 1), s * offv);  // mid-chunk arg const
    B[6] = w;
    B[7] = 0.0f;

    if (k == 0) {
        scalars[0] = 1.0f / (1.0f + expf(-po[0]));  // phase offset, REVOLUTIONS
        scalars[1] = 1.0f / tmax;
        scalars[2] = dt;
    }
}

// ---------------------------------------------------------------------------
// Chebyshev oscillator state: cos/sin sequences advanced with the 3-term
// recurrence x_{j+1} = 2cos(th)*x_j - x_{j-1}  (1 fma per step per sequence;
// c2 stays in SGPR). The weighted envelope is FROZEN at the chunk midpoint
// (error <= |b'|*da/2 ~ 4e-4 weighted).
// ---------------------------------------------------------------------------
struct Cheb {
    float c2;              // 2cos(theta) (wave-uniform -> SGPR)
    float xc0, xc1;        // cos sequence: x_j, x_{j+1}
    float xs0, xs1;        // sin sequence
    float wb, wbf;         // frozen weighted bell, and f * wb
};

__device__ __forceinline__ void osc_setup(const float* __restrict__ b,
                                          float t0, float tn0, float sig,
                                          Cheb& o)
{
    const float f  = b[0];
    const float cd = b[1];
    const float sd = b[2];
    o.c2           = b[3];

    // exact phase at chunk start (Dekker product + Sterbenz frac), revolutions
    const float hi  = f * t0;
    const float lo  = fmaf(f, t0, -hi);
    const float rev = (hi - floorf(hi)) + lo + sig;
    o.xc0 = __builtin_amdgcn_cosf(rev);            // cos(2*pi*rev)
    o.xs0 = __builtin_amdgcn_sinf(rev);

    // second point: rotate once by theta
    o.xc1 = fmaf(-o.xs0, sd, o.xc0 * cd);
    o.xs1 = fmaf( o.xs0, cd, o.xc0 * sd);

    // frozen mid-chunk weighted envelope
    const float a    = fmaf(b[4], tn0, b[5]);
    const float bell = __builtin_amdgcn_rsqf(fmaf(a, a, 1.0f));
    o.wb  = bell * b[6];
    o.wbf = o.wb * f;
}

#define CHEB_ADV(o)                                                   \
    {                                                                 \
        const float nxc = fmaf(o.c2, o.xc1, -o.xc0);                  \
        o.xc0 = o.xc1; o.xc1 = nxc;                                   \
        const float nxs = fmaf(o.c2, o.xs1, -o.xs0);                  \
        o.xs0 = o.xs1; o.xs1 = nxs;                                   \
    }

// ---------------------------------------------------------------------------
// Main kernel: each block = 4 waves; the 4 waves split the 64 oscillators of
// each bank 4-ways (16 osc per thread), with WAVE-UNIFORM bank pointers
// (s_load path). Each of the 64 lanes owns one chunk of 8 samples.
// Cross-wave partials combine through padded LDS (stride 9 floats -> no bank
// conflicts). Final combine is distributed: wave p writes samples {2p,2p+1}.
//
// Carrier FM factorization: sum_k wb sin(A_k + m) = cm*S + sm*C;
// first-order time-jitter correction via Sf = sum f*wb*sinA, Cf = sum f*wb*cosA:
//   out_j = cm*S + sm*C + d2p_j*(cm*Cf - sm*Sf).
// ---------------------------------------------------------------------------
__global__ void __launch_bounds__(256, 4) fm_main_kernel(
    const float* __restrict__ t,
    const float* __restrict__ banks,
    const float* __restrict__ scalars,
    float* __restrict__ out, int T)
{
    const int c  = threadIdx.x & 63;                                   // chunk lane
    const int p  = __builtin_amdgcn_readfirstlane(threadIdx.x >> 6);   // wave id
    const int i0 = (blockIdx.x * 64 + c) * CHUNK;                      // sample base

    __shared__ float modbuf[NSPLIT][64][CHUNK + 1];   // pad -> conflict-free
    __shared__ float outbuf[NSPLIT][64][CHUNK + 1];

    const float sig     = scalars[0];
    const float invtmax = scalars[1];
    const float dt      = scalars[2];

    const float4 ta = *reinterpret_cast<const float4*>(t + i0);
    const float4 tb = *reinterpret_cast<const float4*>(t + i0 + 4);
    const float tj[CHUNK] = {ta.x, ta.y, ta.z, ta.w, tb.x, tb.y, tb.z, tb.w};
    const float t0 = tj[0];

    // 2*pi * (t_j - (t0 + j*dt)): f32 rounding jitter of t, radians per Hz
    float d2p[CHUNK];
    d2p[0] = 0.0f;
#pragma unroll
    for (int j = 1; j < CHUNK; ++j)
        d2p[j] = TWO_PI_F * fmaf(-(float)j, dt, tj[j] - t0);

    const float tn0 = fmaf(t0, invtmax, -0.5f);

    // ---------------- modulator bank (16 osc): Cm = sum wb*cos, Sfm = sum wbf*sin
    float Cm[CHUNK], Sfm[CHUNK];
#pragma unroll
    for (int j = 0; j < CHUNK; ++j) { Cm[j] = 0.0f; Sfm[j] = 0.0f; }

    {
        const float* base = banks + (p * 16) * 8;      // wave-uniform pointer
#pragma unroll 1
        for (int q = 0; q < QH; ++q) {
            const float* B = base + q * 32;            // 4 oscillators per group
            Cheb o0, o1, o2, o3;
            osc_setup(B +  0, t0, tn0, sig, o0);
            osc_setup(B +  8, t0, tn0, sig, o1);
            osc_setup(B + 16, t0, tn0, sig, o2);
            osc_setup(B + 24, t0, tn0, sig, o3);

#pragma unroll
            for (int j = 0; j < CHUNK; ++j) {
#define MOD_STEP(o)                                                   \
                {                                                     \
                    Cm[j]  = fmaf(o.wb,  o.xc0, Cm[j]);               \
                    Sfm[j] = fmaf(o.wbf, o.xs0, Sfm[j]);              \
                }
                MOD_STEP(o0) MOD_STEP(o1) MOD_STEP(o2) MOD_STEP(o3)
#undef MOD_STEP
                if (j < CHUNK - 1) {
                    CHEB_ADV(o0) CHEB_ADV(o1) CHEB_ADV(o2) CHEB_ADV(o3)
                }
            }
        }
    }

    // publish partial mod (jitter-corrected), combine across the 4 waves
#pragma unroll
    for (int j = 0; j < CHUNK; ++j)
        modbuf[p][c][j] = fmaf(-d2p[j], Sfm[j], Cm[j]);
    __syncthreads();

    float cm[CHUNK], sm[CHUNK];
#pragma unroll
    for (int j = 0; j < CHUNK; ++j) {
        const float m = ((modbuf[0][c][j] + modbuf[1][c][j])
                        + modbuf[2][c][j]) + modbuf[3][c][j];
        const float mrev = m * INV2PI_F;
        cm[j] = __builtin_amdgcn_cosf(mrev);
        sm[j] = __builtin_amdgcn_sinf(mrev);
    }

    // ---------------- carrier bank (16 osc): S, C, Sf, Cf sums --------------
    float S[CHUNK], C[CHUNK], Sf[CHUNK], Cf[CHUNK];
#pragma unroll
    for (int j = 0; j < CHUNK; ++j) { S[j] = 0.0f; C[j] = 0.0f;
                                      Sf[j] = 0.0f; Cf[j] = 0.0f; }

    {
        const float* base = banks + (KOSC + p * 16) * 8;   // wave-uniform
#pragma unroll 1
        for (int q = 0; q < QH; ++q) {
            const float* B = base + q * 32;
            Cheb o0, o1, o2, o3;
            osc_setup(B +  0, t0, tn0, sig, o0);
            osc_setup(B +  8, t0, tn0, sig, o1);
            osc_setup(B + 16, t0, tn0, sig, o2);
            osc_setup(B + 24, t0, tn0, sig, o3);

#pragma unroll
            for (int j = 0; j < CHUNK; ++j) {
#define CAR_STEP(o)                                                   \
                {                                                     \
                    S[j]  = fmaf(o.wb,  o.xs0, S[j]);                 \
                    C[j]  = fmaf(o.wb,  o.xc0, C[j]);                 \
                    Sf[j] = fmaf(o.wbf, o.xs0, Sf[j]);                \
                    Cf[j] = fmaf(o.wbf, o.xc0, Cf[j]);                \
                }
                CAR_STEP(o0) CAR_STEP(o1) CAR_STEP(o2) CAR_STEP(o3)
#undef CAR_STEP
                if (j < CHUNK - 1) {
                    CHEB_ADV(o0) CHEB_ADV(o1) CHEB_ADV(o2) CHEB_ADV(o3)
                }
            }
        }
    }

    // epilogue: FM rotation + jitter correction -> per-wave partial output
#pragma unroll
    for (int j = 0; j < CHUNK; ++j) {
        float u = cm[j] * S[j];
        u = fmaf(sm[j], C[j], u);
        float v = cm[j] * Cf[j];
        v = fmaf(-sm[j], Sf[j], v);
        outbuf[p][c][j] = fmaf(d2p[j], v, u);
    }
    __syncthreads();

    // distributed combine: wave p sums and stores samples {2p, 2p+1}
    {
        const int j0 = 2 * p;
        const float o0 = ((outbuf[0][c][j0]     + outbuf[1][c][j0])
                         + outbuf[2][c][j0])    + outbuf[3][c][j0];
        const float o1 = ((outbuf[0][c][j0 + 1] + outbuf[1][c][j0 + 1])
                         + outbuf[2][c][j0 + 1]) + outbuf[3][c][j0 + 1];
        *reinterpret_cast<float2*>(out + i0 + j0) = make_float2(o0, o1);
    }
}

// ---------------------------------------------------------------------------
extern "C" void kernel_launch(void* const* d_in, const int* in_sizes, int n_in,
                              void* d_out, int out_size, void* d_ws, size_t ws_size,
                              hipStream_t stream) {
    // setup_inputs() order:
    // 0:t 1:carrier_fq 2:carrier_weight 3:mod_fq 4:mod_weight 5:phase_offset
    // 6:carrier_env_slope 7:carrier_env_offset 8:mod_env_slope 9:mod_env_offset
    const float* t   = (const float*)d_in[0];
    const float* cfq = (const float*)d_in[1];
    const float* cw  = (const float*)d_in[2];
    const float* mfq = (const float*)d_in[3];
    const float* mw  = (const float*)d_in[4];
    const float* po  = (const float*)d_in[5];
    const float* ces = (const float*)d_in[6];
    const float* ceo = (const float*)d_in[7];
    const float* mes = (const float*)d_in[8];
    const float* meo = (const float*)d_in[9];
    const int T = in_sizes[0];

    float* banks   = (float*)d_ws;                       // 128 osc * 8 floats
    float* scalars = banks + 2 * KOSC * 8;               // 3 floats

    precompute_kernel<<<1, 2 * KOSC, 0, stream>>>(t, T, cfq, cw, mfq, mw, po,
                                                  ces, ceo, mes, meo,
                                                  banks, scalars);

    // one block = 4 waves = 64 chunks of 8 samples
    const int grid = T / (CHUNK * 64);        // 2048 blocks for T = 1<<20
    fm_main_kernel<<<grid, 256, 0, stream>>>(t, banks, scalars,
                                             (float*)d_out, T);
}